// Round 6
// baseline (37.993 us; speedup 1.0000x reference)
//
#include <hip/hip_runtime.h>
#include <hip/hip_bf16.h>

#define B_TOTAL 2048
#define IN_SZ   288
#define GH      64
#define E_NUM   8
#define OUT_N   256
#define K_TOT   (E_NUM * IN_SZ)   // 2304

#define WT2_BLOCKS 576            // 72 k-slabs x 8 o-slabs

typedef __attribute__((ext_vector_type(8))) short bf16x8;
typedef __attribute__((ext_vector_type(4))) float f32x4;

__device__ __forceinline__ float elu_f(float x) {
    return x > 0.0f ? x : (expf(x) - 1.0f);
}
__device__ __forceinline__ ushort f2bf(float f) {
    __hip_bfloat16 h = __float2bfloat16(f);
    return *reinterpret_cast<ushort*>(&h);
}

// ================= k1: w2 [2304][256] f32 -> w2t [256][2304] bf16 =================
// 576 uniform blocks, one 32x32 tile each (validated r5 mapping).
__global__ __launch_bounds__(256) void trans_kernel(
    const float* __restrict__ w2, ushort* __restrict__ w2t)
{
    __shared__ float ts[32][33];
    const int t = threadIdx.x;
    const int k0 = (blockIdx.x >> 3) * 32;
    const int o0 = (blockIdx.x & 7) * 32;
    #pragma unroll
    for (int idx = t; idx < 1024; idx += 256) {
        int r = idx >> 5, c = idx & 31;
        ts[r][c] = w2[(size_t)(k0 + r) * OUT_N + o0 + c];
    }
    __syncthreads();
    #pragma unroll
    for (int idx = t; idx < 1024; idx += 256) {
        int r = idx >> 5, c = idx & 31;   // r = o-off, c = k-off
        w2t[(size_t)(o0 + r) * K_TOT + k0 + c] = f2bf(ts[c][r]);
    }
}

// ================= k2: fused gate MLP + barrier-free GEMM =================
// grid (32, 8): block = 64 rows x 32 cols; wave = 16 rows.
// Gate recomputed per block for its 64 rows (cheap MFMA), softmax in-block,
// then per-expert accumulator scaling with A-frags in registers, B from w2t (L2).
__global__ __launch_bounds__(256, 1) void fused_kernel(
    const float* __restrict__ z,
    const float* __restrict__ g0_w, const float* __restrict__ g0_b,
    const float* __restrict__ g1_w, const float* __restrict__ g1_b,
    const float* __restrict__ g2_w, const float* __restrict__ g2_b,
    const ushort* __restrict__ w2t, const float* __restrict__ b2,
    float* __restrict__ out)
{
    // ---- LDS carve (62720 B) ----
    // R0 [0,37888): zbs [64][296] bf16  -> reused as g0t [64][296] bf16
    // g1t  [37888,47104): [64][72] bf16
    // g2t  [47104,49408): [16][72] bf16 (rows 8-15 zero)
    // hscr [49408,58624): per-wave [16][72] bf16 x 4
    // lgs  [58624,60672): [64][8] f32
    // cfs  [60672,62720): [64][8] f32
    __shared__ char smem[62720];
    ushort* zbs  = (ushort*)smem;
    ushort* g0t  = (ushort*)smem;
    ushort* g1t  = (ushort*)(smem + 37888);
    ushort* g2t  = (ushort*)(smem + 47104);
    float*  lgs  = (float*)(smem + 58624);
    float*  cfs  = (float*)(smem + 60672);

    const int t   = threadIdx.x;
    const int wid = t >> 6, l = t & 63;
    const int r0  = blockIdx.x * 64;          // block's first row
    const int n0  = blockIdx.y * 32;          // block's first col
    ushort* hscr = (ushort*)(smem + 49408) + wid * 1152;   // [16][72]

    const int frow = l & 15;                  // fragment row / col lane
    const int fk   = (l >> 4) * 8;            // fragment k-offset

    // ---- phase 1: stage zbs (bf16) + g1t + g2t ----
    for (int q = t; q < 4608; q += 256) {            // 64 rows x 72 float4
        int row = q / 72, c4 = q - row * 72;
        float4 v = *(const float4*)(z + (size_t)(r0 + row) * IN_SZ + c4 * 4);
        ushort4 o4;
        o4.x = f2bf(v.x); o4.y = f2bf(v.y); o4.z = f2bf(v.z); o4.w = f2bf(v.w);
        *(ushort4*)&zbs[row * 296 + c4 * 4] = o4;
    }
    for (int q = t; q < 4096; q += 256) {            // g1_w[i][o] -> g1t[o][i]
        int i = q >> 6, o = q & 63;
        g1t[o * 72 + i] = f2bf(g1_w[q]);
    }
    for (int q = t; q < 512; q += 256) {             // g2_w[i][o] -> g2t[o][i]
        int i = q >> 3, o = q & 7;
        g2t[o * 72 + i] = f2bf(g2_w[q]);
    }
    for (int q = t; q < 576; q += 256) g2t[576 + q] = 0;   // pad rows 8-15
    __syncthreads();

    // ---- phase 2: A-fragments for this wave's 16 rows (used by gate L0 AND gemm) ----
    bf16x8 A[9];
    #pragma unroll
    for (int kk = 0; kk < 9; ++kk)
        A[kk] = *(const bf16x8*)&zbs[(wid * 16 + frow) * 296 + kk * 32 + fk];
    __syncthreads();   // A-reads drained before g0t overwrites zbs

    // ---- phase 3: stage g0t (overwrites zbs region) ----
    for (int q = t; q < 18432; q += 256) {           // g0_w[i][o] -> g0t[o][i]
        int i = q >> 6, o = q & 63;
        g0t[o * 296 + i] = f2bf(g0_w[q]);
    }
    __syncthreads();

    // ---- gate layer 0: [16x288] @ g0t^T -> h0 [16x64] (per wave) ----
    #pragma unroll
    for (int nt = 0; nt < 4; ++nt) {
        f32x4 g = {0.f, 0.f, 0.f, 0.f};
        #pragma unroll
        for (int kk = 0; kk < 9; ++kk) {
            bf16x8 b = *(const bf16x8*)&g0t[(nt * 16 + frow) * 296 + kk * 32 + fk];
            g = __builtin_amdgcn_mfma_f32_16x16x32_bf16(A[kk], b, g, 0, 0, 0);
        }
        float bias = g0_b[nt * 16 + frow];
        #pragma unroll
        for (int j = 0; j < 4; ++j)
            hscr[((l >> 4) * 4 + j) * 72 + nt * 16 + frow] = f2bf(elu_f(g[j] + bias));
    }

    // ---- gate layer 1: [16x64] @ g1t^T (hscr reused h0 -> h1) ----
    {
        bf16x8 hA[2];
        #pragma unroll
        for (int kk = 0; kk < 2; ++kk)
            hA[kk] = *(const bf16x8*)&hscr[frow * 72 + kk * 32 + fk];
        #pragma unroll
        for (int nt = 0; nt < 4; ++nt) {
            f32x4 g = {0.f, 0.f, 0.f, 0.f};
            #pragma unroll
            for (int kk = 0; kk < 2; ++kk) {
                bf16x8 b = *(const bf16x8*)&g1t[(nt * 16 + frow) * 72 + kk * 32 + fk];
                g = __builtin_amdgcn_mfma_f32_16x16x32_bf16(hA[kk], b, g, 0, 0, 0);
            }
            float bias = g1_b[nt * 16 + frow];
            #pragma unroll
            for (int j = 0; j < 4; ++j)
                hscr[((l >> 4) * 4 + j) * 72 + nt * 16 + frow] = f2bf(elu_f(g[j] + bias));
        }
    }

    // ---- gate layer 2: [16x64] @ g2t^T -> logits [16x8] ----
    {
        bf16x8 hA[2];
        #pragma unroll
        for (int kk = 0; kk < 2; ++kk)
            hA[kk] = *(const bf16x8*)&hscr[frow * 72 + kk * 32 + fk];
        f32x4 g = {0.f, 0.f, 0.f, 0.f};
        #pragma unroll
        for (int kk = 0; kk < 2; ++kk) {
            bf16x8 b = *(const bf16x8*)&g2t[frow * 72 + kk * 32 + fk];
            g = __builtin_amdgcn_mfma_f32_16x16x32_bf16(hA[kk], b, g, 0, 0, 0);
        }
        if (frow < E_NUM) {
            float bias = g2_b[frow];
            #pragma unroll
            for (int j = 0; j < 4; ++j)
                lgs[(wid * 16 + (l >> 4) * 4 + j) * 8 + frow] = g[j] + bias;
        }
    }
    __syncthreads();

    // ---- softmax per row: t<64 -> row t ----
    if (t < 64) {
        float m = lgs[t * 8];
        #pragma unroll
        for (int k = 1; k < E_NUM; ++k) m = fmaxf(m, lgs[t * 8 + k]);
        float s = 0.f;
        float ex[E_NUM];
        #pragma unroll
        for (int k = 0; k < E_NUM; ++k) { ex[k] = expf(lgs[t * 8 + k] - m); s += ex[k]; }
        float inv = 1.0f / s;
        #pragma unroll
        for (int k = 0; k < E_NUM; ++k) cfs[t * 8 + k] = ex[k] * inv;
    }
    __syncthreads();

    // ---- coef for this lane's 4 C-rows ----
    float cf[4][E_NUM];
    #pragma unroll
    for (int j = 0; j < 4; ++j) {
        const float4* cp = (const float4*)&cfs[(wid * 16 + (l >> 4) * 4 + j) * 8];
        float4 c0 = cp[0], c1 = cp[1];
        cf[j][0] = c0.x; cf[j][1] = c0.y; cf[j][2] = c0.z; cf[j][3] = c0.w;
        cf[j][4] = c1.x; cf[j][5] = c1.y; cf[j][6] = c1.z; cf[j][7] = c1.w;
    }

    // ---- main GEMM: per-expert partials, scaled accumulate (r5-validated) ----
    f32x4 acc0 = {0.f, 0.f, 0.f, 0.f};
    f32x4 acc1 = {0.f, 0.f, 0.f, 0.f};
    const ushort* B0 = w2t + (size_t)(n0 + frow) * K_TOT + fk;
    const ushort* B1 = w2t + (size_t)(n0 + 16 + frow) * K_TOT + fk;

    #pragma unroll 2
    for (int e = 0; e < E_NUM; ++e) {
        f32x4 p0 = {0.f, 0.f, 0.f, 0.f};
        f32x4 p1 = {0.f, 0.f, 0.f, 0.f};
        #pragma unroll
        for (int kk = 0; kk < 9; ++kk) {
            bf16x8 b0 = *(const bf16x8*)(B0 + e * IN_SZ + kk * 32);
            bf16x8 b1 = *(const bf16x8*)(B1 + e * IN_SZ + kk * 32);
            p0 = __builtin_amdgcn_mfma_f32_16x16x32_bf16(A[kk], b0, p0, 0, 0, 0);
            p1 = __builtin_amdgcn_mfma_f32_16x16x32_bf16(A[kk], b1, p1, 0, 0, 0);
        }
        #pragma unroll
        for (int j = 0; j < 4; ++j) {
            acc0[j] = fmaf(cf[j][e], p0[j], acc0[j]);
            acc1[j] = fmaf(cf[j][e], p1[j], acc1[j]);
        }
    }

    // ---- epilogue: mixed bias + store ----
    const int col0 = n0 + frow, col1 = n0 + 16 + frow;
    #pragma unroll
    for (int j = 0; j < 4; ++j) {
        const int row = r0 + wid * 16 + (l >> 4) * 4 + j;
        float b0v = 0.f, b1v = 0.f;
        #pragma unroll
        for (int e = 0; e < E_NUM; ++e) {
            b0v = fmaf(cf[j][e], b2[e * OUT_N + col0], b0v);
            b1v = fmaf(cf[j][e], b2[e * OUT_N + col1], b1v);
        }
        out[(size_t)row * OUT_N + col0] = acc0[j] + b0v;
        out[(size_t)row * OUT_N + col1] = acc1[j] + b1v;
    }
}

// ================= fallback (ws too small): f32 gate + direct =================
__global__ __launch_bounds__(64) void gate_fb_kernel(
    const float* __restrict__ z,
    const float* __restrict__ g0_w, const float* __restrict__ g0_b,
    const float* __restrict__ g1_w, const float* __restrict__ g1_b,
    const float* __restrict__ g2_w, const float* __restrict__ g2_b,
    float* __restrict__ coef)
{
    __shared__ float z_s[IN_SZ];
    __shared__ float h0_s[GH];
    __shared__ float h1_s[GH];
    const int b = blockIdx.x;
    const int t = threadIdx.x;
    const float* zr = z + (size_t)b * IN_SZ;
    for (int i = t; i < IN_SZ; i += 64) z_s[i] = zr[i];
    __syncthreads();
    float a0 = g0_b[t];
    for (int i = 0; i < IN_SZ; ++i) a0 = fmaf(z_s[i], g0_w[i * GH + t], a0);
    h0_s[t] = elu_f(a0);
    __syncthreads();
    float a1 = g1_b[t];
    for (int k = 0; k < GH; ++k) a1 = fmaf(h0_s[k], g1_w[k * GH + t], a1);
    h1_s[t] = elu_f(a1);
    __syncthreads();
    if (t < E_NUM) {
        float lg = g2_b[t];
        for (int k = 0; k < GH; ++k) lg = fmaf(h1_s[k], g2_w[k * E_NUM + t], lg);
        float m = lg;
        for (int d = 1; d < 8; d <<= 1) m = fmaxf(m, __shfl_xor(m, d, 8));
        float ex = expf(lg - m);
        float s = ex;
        for (int d = 1; d < 8; d <<= 1) s += __shfl_xor(s, d, 8);
        coef[b * E_NUM + t] = ex / s;
    }
}

__global__ __launch_bounds__(256) void direct_kernel(
    const float* __restrict__ z, const float* __restrict__ w2,
    const float* __restrict__ b2, const float* __restrict__ coef,
    float* __restrict__ out)
{
    __shared__ float z_s[8][IN_SZ];
    __shared__ float c_s[8][E_NUM];
    const int b0 = blockIdx.x * 8;
    const int t  = threadIdx.x;
    for (int idx = t; idx < 8 * IN_SZ; idx += 256)
        ((float*)z_s)[idx] = z[(size_t)b0 * IN_SZ + idx];
    if (t < 64) c_s[t >> 3][t & 7] = coef[b0 * E_NUM + t];
    __syncthreads();
    float outv[8];
    #pragma unroll
    for (int r = 0; r < 8; ++r) outv[r] = 0.0f;
    for (int e = 0; e < E_NUM; ++e) {
        const float* w = w2 + (size_t)e * IN_SZ * OUT_N + t;
        float tmp[8];
        #pragma unroll
        for (int r = 0; r < 8; ++r) tmp[r] = 0.0f;
        #pragma unroll 4
        for (int i = 0; i < IN_SZ; ++i) {
            float wv = w[i * OUT_N];
            #pragma unroll
            for (int r = 0; r < 8; ++r) tmp[r] += z_s[r][i] * wv;
        }
        float bv = b2[e * OUT_N + t];
        #pragma unroll
        for (int r = 0; r < 8; ++r) outv[r] += c_s[r][e] * (tmp[r] + bv);
    }
    #pragma unroll
    for (int r = 0; r < 8; ++r) out[(size_t)(b0 + r) * OUT_N + t] = outv[r];
}

extern "C" void kernel_launch(void* const* d_in, const int* in_sizes, int n_in,
                              void* d_out, int out_size, void* d_ws, size_t ws_size,
                              hipStream_t stream) {
    const float* z    = (const float*)d_in[0];
    const float* g0_w = (const float*)d_in[1];
    const float* g0_b = (const float*)d_in[2];
    const float* g1_w = (const float*)d_in[3];
    const float* g1_b = (const float*)d_in[4];
    const float* g2_w = (const float*)d_in[5];
    const float* g2_b = (const float*)d_in[6];
    // d_in[7..10] = w0,b0,w1,b1 are dead in the reference (layer_out never fed back)
    const float* w2   = (const float*)d_in[11];
    const float* b2   = (const float*)d_in[12];
    float* out = (float*)d_out;

    const size_t w2t_b = (size_t)OUT_N * K_TOT * sizeof(ushort);   // 1.18 MB

    if (ws_size >= w2t_b + 65536) {
        ushort* w2t = (ushort*)d_ws;
        trans_kernel<<<WT2_BLOCKS, 256, 0, stream>>>(w2, w2t);
        fused_kernel<<<dim3(B_TOTAL / 64, OUT_N / 32), 256, 0, stream>>>(
            z, g0_w, g0_b, g1_w, g1_b, g2_w, g2_b, w2t, b2, out);
    } else {
        float* coef = (float*)d_ws;   // needs only 64 KB
        gate_fb_kernel<<<B_TOTAL, 64, 0, stream>>>(z, g0_w, g0_b, g1_w, g1_b,
                                                   g2_w, g2_b, coef);
        direct_kernel<<<B_TOTAL / 8, 256, 0, stream>>>(z, w2, b2, coef, out);
    }
}